// Round 17
// baseline (402.830 us; speedup 1.0000x reference)
//
#include <hip/hip_runtime.h>

#define NN 50000
#define NPAD 50048   // rows padded to multiple of 64 for MFMA tiles
#define NE 800000
#define FIN 64
#define H 128
#define NG 16
#define POOL_BLOCKS 200
#define POOL_NODES 250
#define NBUCK 98         // buckets of 512 dst nodes
#define BUCK_CAP 10000   // edges per bucket capacity (expected 8163 +- 90)
#define FILLA_BLOCKS 512
#define FILLA_CHUNK 1563  // ceil(NE / FILLA_BLOCKS)
#define CHUNK_U 16       // uints per node per feature-chunk (32 feats)
#define DUMMY NN         // zero pad row used for CSR padding
#define AGG_CH (NN / 16) // 3125 blocks per chunk
#define PREP_ITEMS (NPAD * FIN + H * FIN + 3 * H * H)
#define PREP_BLOCKS ((PREP_ITEMS + 255) / 256)

typedef __bf16 bf16x8 __attribute__((ext_vector_type(8)));
typedef float f32x4 __attribute__((ext_vector_type(4)));

// ---- helpers ----
__device__ inline unsigned short bf16r(float x) {
    unsigned int u = __float_as_uint(x);
    return (unsigned short)((u + 0x7fffu + ((u >> 16) & 1u)) >> 16);
}
__device__ inline unsigned int pack_bf16x2(float a, float b) {
    return (unsigned int)bf16r(a) | ((unsigned int)bf16r(b) << 16);
}
__device__ inline float bf_lo(unsigned int u) { return __uint_as_float(u << 16); }
__device__ inline float bf_hi(unsigned int u) { return __uint_as_float(u & 0xffff0000u); }

// ====== fillA + prep merged: blocks [0,512) bucket edges; rest convert x/W ======
__global__ __launch_bounds__(256) void fillA_prep_kernel(const int* __restrict__ ei,
                                                         int* __restrict__ gcount,
                                                         unsigned int* __restrict__ ebuf,
                                                         float* __restrict__ pooled,
                                                         const float* __restrict__ x,
                                                         const float* __restrict__ W1,
                                                         const float* __restrict__ W2,
                                                         const float* __restrict__ W3,
                                                         const float* __restrict__ W4,
                                                         unsigned short* __restrict__ xb,
                                                         unsigned short* __restrict__ Wt1,
                                                         unsigned short* __restrict__ Wt2,
                                                         unsigned short* __restrict__ Wt3,
                                                         unsigned short* __restrict__ Wt4) {
    const int t = threadIdx.x;
    if (blockIdx.x >= FILLA_BLOCKS) {
        // ---- prep part ----
        int e = (blockIdx.x - FILLA_BLOCKS) * 256 + t;
        if (e < NPAD * FIN) {
            int n = e >> 6, k = e & 63;
            unsigned short v = (n < NN) ? bf16r(x[n * FIN + k]) : (unsigned short)0;
            xb[(size_t)(k >> 5) * (NPAD * 32) + n * 32 + (k & 31)] = v;
            return;
        }
        int tt = e - NPAD * FIN;
        if (tt < H * FIN) {
            int n = tt / FIN, k = tt % FIN;
            Wt1[tt] = bf16r(W1[k * H + n]);
            return;
        }
        int u = tt - H * FIN;
        const float* W = W2;
        unsigned short* Wt = Wt2;
        if (u >= 2 * H * H) { W = W4; Wt = Wt4; u -= 2 * H * H; }
        else if (u >= H * H) { W = W3; Wt = Wt3; u -= H * H; }
        if (u < H * H) {
            int n = u / H, k = u % H;
            Wt[u] = bf16r(W[k * H + n]);
        }
        return;
    }
    // ---- fillA part ----
    __shared__ int hist[128];
    __shared__ int base[128];
    if (blockIdx.x == 0)
        for (int i = t; i < NG * H + NG; i += 256) pooled[i] = 0.f;
    if (t < 128) hist[t] = 0;
    __syncthreads();
    const int e0 = blockIdx.x * FILLA_CHUNK;
    const int e1 = min(e0 + FILLA_CHUNK, NE);
    for (int e = e0 + t; e < e1; e += 256)
        atomicAdd(&hist[ei[NE + e] >> 9], 1);
    __syncthreads();
    if (t < 128) {
        int h = (t < NBUCK) ? hist[t] : 0;
        base[t] = h ? atomicAdd(&gcount[t], h) : 0;
    }
    __syncthreads();
    for (int e = e0 + t; e < e1; e += 256) {
        int d = ei[NE + e];
        int s = ei[e];
        int b = d >> 9;
        int pos = atomicAdd(&base[b], 1);
        ebuf[b * BUCK_CAP + pos] = (unsigned int)s | ((unsigned int)d << 16);
    }
}

// fillB (fused hist+scan+scatter): per bucket: LDS hist -> padded counts ->
// local scan -> one global atomicAdd reserves the bucket's csr window ->
// rowse (start,end) + dinv + LDS-cursor scatter + DUMMY pads.
__global__ __launch_bounds__(256) void fillB_kernel(const unsigned int* __restrict__ ebuf,
                                                    const int* __restrict__ gcount,
                                                    int* __restrict__ galloc,
                                                    int2* __restrict__ rowse,
                                                    float* __restrict__ dinv,
                                                    unsigned short* __restrict__ csr) {
    __shared__ int lh[512];
    __shared__ int lsum[256];
    __shared__ int loff[512];
    __shared__ int lcur[512];
    __shared__ int base_s;
    const int b = blockIdx.x, t = threadIdx.x;
    const int n0 = b * 512;
    lh[t] = 0;
    lh[t + 256] = 0;
    __syncthreads();
    const int ne = gcount[b];
    const unsigned int* __restrict__ eb = ebuf + b * BUCK_CAP;
    for (int i = t; i < ne; i += 256)
        atomicAdd(&lh[(int)(eb[i] >> 16) - n0], 1);
    __syncthreads();
    const int c0 = lh[2 * t], c1 = lh[2 * t + 1];
    const int p0 = (c0 + 7) & ~7, p1 = (c1 + 7) & ~7;
    lsum[t] = p0 + p1;
    __syncthreads();
    for (int off = 1; off < 256; off <<= 1) {
        int u = (t >= off) ? lsum[t - off] : 0;
        __syncthreads();
        lsum[t] += u;
        __syncthreads();
    }
    if (t == 255) base_s = atomicAdd(galloc, lsum[255]);
    int excl = (t == 0) ? 0 : lsum[t - 1];
    __syncthreads();
    const int base = base_s;
    loff[2 * t] = excl;
    loff[2 * t + 1] = excl + p0;
    {
        int j = 2 * t, n = n0 + j;
        int st = base + excl;
        if (n < NN) {
            rowse[n] = make_int2(st, st + p0);
            dinv[n] = rsqrtf((float)c0 + 1.0f);  // +1 self-loop
        } else if (n < NPAD) {
            rowse[n] = make_int2(0, 0);
            dinv[n] = 0.0f;
        }
        lcur[j] = st;
        int st1 = st + p0, n1 = n + 1;
        if (n1 < NN) {
            rowse[n1] = make_int2(st1, st1 + p1);
            dinv[n1] = rsqrtf((float)c1 + 1.0f);
        } else if (n1 < NPAD) {
            rowse[n1] = make_int2(0, 0);
            dinv[n1] = 0.0f;
        }
        lcur[j + 1] = st1;
    }
    __syncthreads();
    for (int i = t; i < ne; i += 256) {
        unsigned int u = eb[i];
        int s = (int)(u & 0xFFFFu);
        int j = (int)(u >> 16) - n0;
        int pos = atomicAdd(&lcur[j], 1);
        csr[pos] = (unsigned short)s;
    }
    __syncthreads();
    {
        int j = 2 * t;
        int st = base + loff[j] + c0, en = base + loff[j] + p0;
        for (int k = st; k < en; k++) csr[k] = (unsigned short)DUMMY;
        int st1 = base + loff[j + 1] + c1, en1 = base + loff[j + 1] + p1;
        for (int k = st1; k < en1; k++) csr[k] = (unsigned short)DUMMY;
    }
}

// ===== MFMA GEMM (chunked in/out): hw' = (h @ W) * dinv[row], bf16 out =====
#define LSTRIDE 130
template <int K>
__global__ __launch_bounds__(256) void gemm_mfma_kernel(const unsigned short* __restrict__ hb,
                                                        const unsigned short* __restrict__ Wt,
                                                        const float* __restrict__ dinv,
                                                        unsigned int* __restrict__ outu) {
    __shared__ float ls[64 * LSTRIDE];  // ~33 KB
    const int wave = threadIdx.x >> 6, lane = threadIdx.x & 63;
    const int m15 = lane & 15, quad = lane >> 4;
    const int row0 = blockIdx.x * 64;
    const int arow = row0 + wave * 16 + m15;

    bf16x8 a[K / 32];
#pragma unroll
    for (int ks = 0; ks < K / 32; ks++)
        a[ks] = *(const bf16x8*)&hb[(size_t)ks * (NPAD * 32) + arow * 32 + quad * 8];

    const int lrow = wave * 16 + quad * 4;
    float dv[4];
#pragma unroll
    for (int r = 0; r < 4; r++) dv[r] = dinv[row0 + lrow + r];

#pragma unroll
    for (int ct = 0; ct < 8; ct++) {
        f32x4 acc = {0.f, 0.f, 0.f, 0.f};
#pragma unroll
        for (int ks = 0; ks < K / 32; ks++) {
            bf16x8 b = *(const bf16x8*)&Wt[(ct * 16 + m15) * K + ks * 32 + quad * 8];
            acc = __builtin_amdgcn_mfma_f32_16x16x32_bf16(a[ks], b, acc, 0, 0, 0);
        }
#pragma unroll
        for (int r = 0; r < 4; r++)
            ls[(lrow + r) * LSTRIDE + ct * 16 + m15] = acc[r] * dv[r];
    }
    __syncthreads();

#pragma unroll
    for (int k = 0; k < 4; k++) {
        int idx = threadIdx.x + 256 * k;
        int c = idx >> 8, row = (idx >> 2) & 63, q = idx & 3;
        const float* p = &ls[row * LSTRIDE + c * 32 + q * 8];
        uint4 o;
        o.x = pack_bf16x2(p[0], p[1]);
        o.y = pack_bf16x2(p[2], p[3]);
        o.z = pack_bf16x2(p[4], p[5]);
        o.w = pack_bf16x2(p[6], p[7]);
        *(uint4*)&outu[(size_t)c * (NPAD * CHUNK_U) + (size_t)(row0 + row) * CHUNK_U + q * 4] = o;
    }
}

// ====== feature-chunked gather aggregation, one node per 16-lane group ======
template <bool RELU_BIAS>
__global__ __launch_bounds__(256) void agg_kernel(const unsigned int* __restrict__ hwc,
                                                  const int2* __restrict__ rowse,
                                                  const unsigned short* __restrict__ csr,
                                                  const float* __restrict__ dinv,
                                                  const float* __restrict__ bias,
                                                  unsigned int* __restrict__ outc) {
    const int chunk = blockIdx.x / AGG_CH;
    const int nb = blockIdx.x % AGG_CH;
    const int wave = threadIdx.x >> 6, lane = threadIdx.x & 63;
    const int g = lane >> 4, u = lane & 15;
    const int n = nb * 16 + wave * 4 + g;
    const unsigned int* __restrict__ slice = hwc + (size_t)chunk * (NPAD * CHUNK_U);

    unsigned int sv = slice[n * CHUNK_U + u];  // self-loop term
    float ax = bf_lo(sv), ay = bf_hi(sv);

    const int2 se = rowse[n];  // start/end, both multiples of 8
    for (int i = se.x; i < se.y; i += 8) {
        uint4 c = *(const uint4*)&csr[i];  // 8 ushort srcs
        int s0 = c.x & 0xFFFF, s1 = c.x >> 16;
        int s2 = c.y & 0xFFFF, s3 = c.y >> 16;
        int s4 = c.z & 0xFFFF, s5 = c.z >> 16;
        int s6 = c.w & 0xFFFF, s7 = c.w >> 16;
        unsigned int v0 = slice[s0 * CHUNK_U + u], v1 = slice[s1 * CHUNK_U + u];
        unsigned int v2 = slice[s2 * CHUNK_U + u], v3 = slice[s3 * CHUNK_U + u];
        unsigned int v4 = slice[s4 * CHUNK_U + u], v5 = slice[s5 * CHUNK_U + u];
        unsigned int v6 = slice[s6 * CHUNK_U + u], v7 = slice[s7 * CHUNK_U + u];
        ax += bf_lo(v0) + bf_lo(v1) + bf_lo(v2) + bf_lo(v3) +
              bf_lo(v4) + bf_lo(v5) + bf_lo(v6) + bf_lo(v7);
        ay += bf_hi(v0) + bf_hi(v1) + bf_hi(v2) + bf_hi(v3) +
              bf_hi(v4) + bf_hi(v5) + bf_hi(v6) + bf_hi(v7);
    }

    float d = dinv[n];
    ax *= d;
    ay *= d;
    if (RELU_BIAS) {
        float2 bv = ((const float2*)bias)[chunk * CHUNK_U + u];
        ax = fmaxf(ax + bv.x, 0.f);
        ay = fmaxf(ay + bv.y, 0.f);
    }
    outc[(size_t)chunk * (NPAD * CHUNK_U) + n * CHUNK_U + u] = pack_bf16x2(ax, ay);
}

// ======== pooling (block-local segment reduction) + last-block MLP ========
__global__ __launch_bounds__(256) void pool_mlp_kernel(const unsigned int* __restrict__ hbu,
                                                       const float* __restrict__ b4,
                                                       const int* __restrict__ batch,
                                                       float* __restrict__ pooled,
                                                       float* __restrict__ cnt,
                                                       int* __restrict__ done,
                                                       const float* __restrict__ lw1,
                                                       const float* __restrict__ lb1,
                                                       const float* __restrict__ lw2,
                                                       const float* __restrict__ lb2,
                                                       float* __restrict__ out) {
    __shared__ int bs[POOL_NODES];
    const int tid = threadIdx.x;
    const int n0 = blockIdx.x * POOL_NODES;
    for (int i = tid; i < POOL_NODES; i += 256) bs[i] = batch[n0 + i];
    __syncthreads();
    const int c2 = tid & 63;                 // feature-uint index 0..63
    const int chunk = c2 >> 4, u = c2 & 15;
    const int rsub = tid >> 6;  // 0..3
    float2 bb = ((const float2*)b4)[c2];
    float2 acc = {0.f, 0.f};
    float cacc = 0.f;
    int curg = bs[rsub];
    const size_t coff = (size_t)chunk * (NPAD * CHUNK_U) + u;
    for (int r = rsub; r < POOL_NODES; r += 4) {
        int g = bs[r];
        if (g != curg) {
            atomicAdd(&pooled[curg * H + c2 * 2], acc.x);
            atomicAdd(&pooled[curg * H + c2 * 2 + 1], acc.y);
            if (c2 == 0) atomicAdd(&cnt[curg], cacc);
            acc.x = acc.y = 0.f;
            cacc = 0.f;
            curg = g;
        }
        unsigned int v = hbu[coff + (size_t)(n0 + r) * CHUNK_U];
        acc.x += bf_lo(v) + bb.x;
        acc.y += bf_hi(v) + bb.y;
        cacc += 1.f;
    }
    atomicAdd(&pooled[curg * H + c2 * 2], acc.x);
    atomicAdd(&pooled[curg * H + c2 * 2 + 1], acc.y);
    if (c2 == 0) atomicAdd(&cnt[curg], cacc);

    // ---- last block runs the MLP ----
    __shared__ int last_s;
    __syncthreads();
    __threadfence();
    if (tid == 0) last_s = (atomicAdd(done, 1) == POOL_BLOCKS - 1) ? 1 : 0;
    __syncthreads();
    if (!last_s) return;
    __threadfence();

    __shared__ float mean_s[NG * H];
    __shared__ float hid_s[NG * 64];
    for (int i = tid; i < NG * H; i += 256) {
        int g = i >> 7;
        float pv = atomicAdd(&pooled[i], 0.f);        // device-scope read
        float cv = atomicAdd(&cnt[g], 0.f);
        mean_s[i] = pv / fmaxf(cv, 1.0f);
    }
    __syncthreads();
    for (int i = tid; i < NG * 64; i += 256) {
        int g = i >> 6, j = i & 63;
        float acc2 = lb1[j];
        for (int f = 0; f < H; f++) acc2 += mean_s[g * H + f] * lw1[f * 64 + j];
        hid_s[i] = fmaxf(acc2, 0.f);
    }
    __syncthreads();
    if (tid < 32) {
        int g = tid >> 1, c = tid & 1;
        float acc2 = lb2[c];
        for (int j = 0; j < 64; j++) acc2 += hid_s[g * 64 + j] * lw2[j * 2 + c];
        out[g * 2 + c] = acc2;
    }
}

extern "C" void kernel_launch(void* const* d_in, const int* in_sizes, int n_in,
                              void* d_out, int out_size, void* d_ws, size_t ws_size,
                              hipStream_t stream) {
    const float* x = (const float*)d_in[0];
    const int* ei = (const int*)d_in[1];
    const int* batch = (const int*)d_in[2];
    const float* W1 = (const float*)d_in[3];
    const float* b1 = (const float*)d_in[4];
    const float* W2 = (const float*)d_in[5];
    const float* b2 = (const float*)d_in[6];
    const float* W3 = (const float*)d_in[7];
    const float* b3 = (const float*)d_in[8];
    const float* W4 = (const float*)d_in[9];
    const float* b4 = (const float*)d_in[10];
    const float* lw1 = (const float*)d_in[11];
    const float* lb1 = (const float*)d_in[12];
    const float* lw2 = (const float*)d_in[13];
    const float* lb2 = (const float*)d_in[14];
    float* out = (float*)d_out;

    // workspace layout (4-byte units; sizes annotated in ints); ~39 MB
    int* wsi = (int*)d_ws;
    int* gcount = wsi;                                      // @0        128
    int* galloc = wsi + 128;                                // @128      1
    int* done = wsi + 130;                                  // @130      1 (memset covers [0,256))
    int2* rowse = (int2*)(wsi + 512);                       // @512      100096 (NPAD int2)
    unsigned short* csr = (unsigned short*)(wsi + 100608);  // @100608   600000 (1.2M ushorts)
    float* dinv = (float*)(wsi + 700608);                   // @700608   50048
    unsigned short* Wt1 = (unsigned short*)(wsi + 750656);  // @750656   4096 (8192 shorts)
    unsigned short* Wt2 = (unsigned short*)(wsi + 754752);  // @754752   8192 (16384 shorts)
    unsigned short* Wt3 = (unsigned short*)(wsi + 762944);  // @762944   8192
    unsigned short* Wt4 = (unsigned short*)(wsi + 771136);  // @771136   8192
    unsigned short* xb = (unsigned short*)(wsi + 779328);   // @779328   1601536 (NPAD*64 shorts)
    unsigned int* hb = (unsigned int*)(wsi + 2380864);      // @2380864  3203072 (NPAD*64 uints)
    unsigned int* hwb = (unsigned int*)(wsi + 5583936);     // @5583936  3203072
    float* pooled = (float*)(wsi + 8787008);                // @8787008  2064 (NG*H+NG)
    float* pcnt = pooled + NG * H;
    unsigned int* ebuf = (unsigned int*)(wsi + 8789072);    // @8789072  980000 -> ends 9769072

    const int gemmBlocks = NPAD / 64;          // 782
    const int aggBlocks = 4 * AGG_CH;          // 12500, chunk-major

    // ---- CSR build + input/weight converts ----
    hipMemsetAsync(gcount, 0, 256 * sizeof(int), stream);  // gcount + galloc + done
    fillA_prep_kernel<<<FILLA_BLOCKS + PREP_BLOCKS, 256, 0, stream>>>(
        ei, gcount, ebuf, pooled, x, W1, W2, W3, W4, xb, Wt1, Wt2, Wt3, Wt4);
    fillB_kernel<<<NBUCK, 256, 0, stream>>>(ebuf, gcount, galloc, rowse, dinv, csr);

    // ---- layer 1 ----
    gemm_mfma_kernel<FIN><<<gemmBlocks, 256, 0, stream>>>(xb, Wt1, dinv, hwb);
    agg_kernel<true><<<aggBlocks, 256, 0, stream>>>(hwb, rowse, csr, dinv, b1, hb);
    // ---- layer 2 ----
    gemm_mfma_kernel<H><<<gemmBlocks, 256, 0, stream>>>((unsigned short*)hb, Wt2, dinv, hwb);
    agg_kernel<true><<<aggBlocks, 256, 0, stream>>>(hwb, rowse, csr, dinv, b2, hb);
    // ---- layer 3 ----
    gemm_mfma_kernel<H><<<gemmBlocks, 256, 0, stream>>>((unsigned short*)hb, Wt3, dinv, hwb);
    agg_kernel<true><<<aggBlocks, 256, 0, stream>>>(hwb, rowse, csr, dinv, b3, hb);
    // ---- layer 4 (no relu/bias; b4 fused in pool) ----
    gemm_mfma_kernel<H><<<gemmBlocks, 256, 0, stream>>>((unsigned short*)hb, Wt4, dinv, hwb);
    agg_kernel<false><<<aggBlocks, 256, 0, stream>>>(hwb, rowse, csr, dinv, nullptr, hb);

    // ---- pooling (fused +b4) + last-block MLP ----
    pool_mlp_kernel<<<POOL_BLOCKS, 256, 0, stream>>>(hb, b4, batch, pooled, pcnt, done,
                                                     lw1, lb1, lw2, lb2, out);
}

// Round 18
// 384.053 us; speedup vs baseline: 1.0489x; 1.0489x over previous
//
#include <hip/hip_runtime.h>

#define NN 50000
#define NPAD 50048   // rows padded to multiple of 64 for MFMA tiles
#define NE 800000
#define FIN 64
#define H 128
#define NG 16
#define POOL_BLOCKS 1000
#define POOL_NODES 50
#define NBUCK 98         // buckets of 512 dst nodes
#define BUCK_CAP 10000   // edges per bucket capacity (expected 8163 +- 90)
#define FILLA_BLOCKS 512
#define FILLA_CHUNK 1563  // ceil(NE / FILLA_BLOCKS)
#define CHUNK_U 16       // uints per node per feature-chunk (32 feats)
#define DUMMY NN         // zero pad row used for CSR padding
#define AGG_CH (NN / 16) // 3125 blocks per chunk
#define PREP_ITEMS (NPAD * FIN + H * FIN + 3 * H * H)
#define PREP_BLOCKS ((PREP_ITEMS + 255) / 256)

typedef __bf16 bf16x8 __attribute__((ext_vector_type(8)));
typedef float f32x4 __attribute__((ext_vector_type(4)));

// ---- helpers ----
__device__ inline unsigned short bf16r(float x) {
    unsigned int u = __float_as_uint(x);
    return (unsigned short)((u + 0x7fffu + ((u >> 16) & 1u)) >> 16);
}
__device__ inline unsigned int pack_bf16x2(float a, float b) {
    return (unsigned int)bf16r(a) | ((unsigned int)bf16r(b) << 16);
}
__device__ inline float bf_lo(unsigned int u) { return __uint_as_float(u << 16); }
__device__ inline float bf_hi(unsigned int u) { return __uint_as_float(u & 0xffff0000u); }

// ====== fillA + prep merged: blocks [0,512) bucket edges; rest convert x/W ======
__global__ __launch_bounds__(256) void fillA_prep_kernel(const int* __restrict__ ei,
                                                         int* __restrict__ gcount,
                                                         unsigned int* __restrict__ ebuf,
                                                         float* __restrict__ pooled,
                                                         const float* __restrict__ x,
                                                         const float* __restrict__ W1,
                                                         const float* __restrict__ W2,
                                                         const float* __restrict__ W3,
                                                         const float* __restrict__ W4,
                                                         unsigned short* __restrict__ xb,
                                                         unsigned short* __restrict__ Wt1,
                                                         unsigned short* __restrict__ Wt2,
                                                         unsigned short* __restrict__ Wt3,
                                                         unsigned short* __restrict__ Wt4) {
    const int t = threadIdx.x;
    if (blockIdx.x >= FILLA_BLOCKS) {
        // ---- prep part ----
        int e = (blockIdx.x - FILLA_BLOCKS) * 256 + t;
        if (e < NPAD * FIN) {
            int n = e >> 6, k = e & 63;
            unsigned short v = (n < NN) ? bf16r(x[n * FIN + k]) : (unsigned short)0;
            xb[(size_t)(k >> 5) * (NPAD * 32) + n * 32 + (k & 31)] = v;
            return;
        }
        int tt = e - NPAD * FIN;
        if (tt < H * FIN) {
            int n = tt / FIN, k = tt % FIN;
            Wt1[tt] = bf16r(W1[k * H + n]);
            return;
        }
        int u = tt - H * FIN;
        const float* W = W2;
        unsigned short* Wt = Wt2;
        if (u >= 2 * H * H) { W = W4; Wt = Wt4; u -= 2 * H * H; }
        else if (u >= H * H) { W = W3; Wt = Wt3; u -= H * H; }
        if (u < H * H) {
            int n = u / H, k = u % H;
            Wt[u] = bf16r(W[k * H + n]);
        }
        return;
    }
    // ---- fillA part ----
    __shared__ int hist[128];
    __shared__ int base[128];
    if (blockIdx.x == 0)
        for (int i = t; i < NG * H + NG; i += 256) pooled[i] = 0.f;
    if (t < 128) hist[t] = 0;
    __syncthreads();
    const int e0 = blockIdx.x * FILLA_CHUNK;
    const int e1 = min(e0 + FILLA_CHUNK, NE);
    for (int e = e0 + t; e < e1; e += 256)
        atomicAdd(&hist[ei[NE + e] >> 9], 1);
    __syncthreads();
    if (t < 128) {
        int h = (t < NBUCK) ? hist[t] : 0;
        base[t] = h ? atomicAdd(&gcount[t], h) : 0;
    }
    __syncthreads();
    for (int e = e0 + t; e < e1; e += 256) {
        int d = ei[NE + e];
        int s = ei[e];
        int b = d >> 9;
        int pos = atomicAdd(&base[b], 1);
        ebuf[b * BUCK_CAP + pos] = (unsigned int)s | ((unsigned int)d << 16);
    }
}

// fillB (fused hist+scan+scatter): per bucket: LDS hist -> padded counts ->
// local scan -> one global atomicAdd reserves the bucket's csr window ->
// rowse (start,end) + dinv + LDS-cursor scatter + DUMMY pads.
__global__ __launch_bounds__(256) void fillB_kernel(const unsigned int* __restrict__ ebuf,
                                                    const int* __restrict__ gcount,
                                                    int* __restrict__ galloc,
                                                    int2* __restrict__ rowse,
                                                    float* __restrict__ dinv,
                                                    unsigned short* __restrict__ csr) {
    __shared__ int lh[512];
    __shared__ int lsum[256];
    __shared__ int loff[512];
    __shared__ int lcur[512];
    __shared__ int base_s;
    const int b = blockIdx.x, t = threadIdx.x;
    const int n0 = b * 512;
    lh[t] = 0;
    lh[t + 256] = 0;
    __syncthreads();
    const int ne = gcount[b];
    const unsigned int* __restrict__ eb = ebuf + b * BUCK_CAP;
    for (int i = t; i < ne; i += 256)
        atomicAdd(&lh[(int)(eb[i] >> 16) - n0], 1);
    __syncthreads();
    const int c0 = lh[2 * t], c1 = lh[2 * t + 1];
    const int p0 = (c0 + 7) & ~7, p1 = (c1 + 7) & ~7;
    lsum[t] = p0 + p1;
    __syncthreads();
    for (int off = 1; off < 256; off <<= 1) {
        int u = (t >= off) ? lsum[t - off] : 0;
        __syncthreads();
        lsum[t] += u;
        __syncthreads();
    }
    if (t == 255) base_s = atomicAdd(galloc, lsum[255]);
    int excl = (t == 0) ? 0 : lsum[t - 1];
    __syncthreads();
    const int base = base_s;
    loff[2 * t] = excl;
    loff[2 * t + 1] = excl + p0;
    {
        int j = 2 * t, n = n0 + j;
        int st = base + excl;
        if (n < NN) {
            rowse[n] = make_int2(st, st + p0);
            dinv[n] = rsqrtf((float)c0 + 1.0f);  // +1 self-loop
        } else if (n < NPAD) {
            rowse[n] = make_int2(0, 0);
            dinv[n] = 0.0f;
        }
        lcur[j] = st;
        int st1 = st + p0, n1 = n + 1;
        if (n1 < NN) {
            rowse[n1] = make_int2(st1, st1 + p1);
            dinv[n1] = rsqrtf((float)c1 + 1.0f);
        } else if (n1 < NPAD) {
            rowse[n1] = make_int2(0, 0);
            dinv[n1] = 0.0f;
        }
        lcur[j + 1] = st1;
    }
    __syncthreads();
    for (int i = t; i < ne; i += 256) {
        unsigned int u = eb[i];
        int s = (int)(u & 0xFFFFu);
        int j = (int)(u >> 16) - n0;
        int pos = atomicAdd(&lcur[j], 1);
        csr[pos] = (unsigned short)s;
    }
    __syncthreads();
    {
        int j = 2 * t;
        int st = base + loff[j] + c0, en = base + loff[j] + p0;
        for (int k = st; k < en; k++) csr[k] = (unsigned short)DUMMY;
        int st1 = base + loff[j + 1] + c1, en1 = base + loff[j + 1] + p1;
        for (int k = st1; k < en1; k++) csr[k] = (unsigned short)DUMMY;
    }
}

// ===== MFMA GEMM (chunked in/out): hw' = (h @ W) * dinv[row], bf16 out =====
#define LSTRIDE 130
template <int K>
__global__ __launch_bounds__(256) void gemm_mfma_kernel(const unsigned short* __restrict__ hb,
                                                        const unsigned short* __restrict__ Wt,
                                                        const float* __restrict__ dinv,
                                                        unsigned int* __restrict__ outu) {
    __shared__ float ls[64 * LSTRIDE];  // ~33 KB
    const int wave = threadIdx.x >> 6, lane = threadIdx.x & 63;
    const int m15 = lane & 15, quad = lane >> 4;
    const int row0 = blockIdx.x * 64;
    const int arow = row0 + wave * 16 + m15;

    bf16x8 a[K / 32];
#pragma unroll
    for (int ks = 0; ks < K / 32; ks++)
        a[ks] = *(const bf16x8*)&hb[(size_t)ks * (NPAD * 32) + arow * 32 + quad * 8];

    const int lrow = wave * 16 + quad * 4;
    float dv[4];
#pragma unroll
    for (int r = 0; r < 4; r++) dv[r] = dinv[row0 + lrow + r];

#pragma unroll
    for (int ct = 0; ct < 8; ct++) {
        f32x4 acc = {0.f, 0.f, 0.f, 0.f};
#pragma unroll
        for (int ks = 0; ks < K / 32; ks++) {
            bf16x8 b = *(const bf16x8*)&Wt[(ct * 16 + m15) * K + ks * 32 + quad * 8];
            acc = __builtin_amdgcn_mfma_f32_16x16x32_bf16(a[ks], b, acc, 0, 0, 0);
        }
#pragma unroll
        for (int r = 0; r < 4; r++)
            ls[(lrow + r) * LSTRIDE + ct * 16 + m15] = acc[r] * dv[r];
    }
    __syncthreads();

#pragma unroll
    for (int k = 0; k < 4; k++) {
        int idx = threadIdx.x + 256 * k;
        int c = idx >> 8, row = (idx >> 2) & 63, q = idx & 3;
        const float* p = &ls[row * LSTRIDE + c * 32 + q * 8];
        uint4 o;
        o.x = pack_bf16x2(p[0], p[1]);
        o.y = pack_bf16x2(p[2], p[3]);
        o.z = pack_bf16x2(p[4], p[5]);
        o.w = pack_bf16x2(p[6], p[7]);
        *(uint4*)&outu[(size_t)c * (NPAD * CHUNK_U) + (size_t)(row0 + row) * CHUNK_U + q * 4] = o;
    }
}

// ====== feature-chunked gather aggregation, one node per 16-lane group ======
template <bool RELU_BIAS>
__global__ __launch_bounds__(256) void agg_kernel(const unsigned int* __restrict__ hwc,
                                                  const int2* __restrict__ rowse,
                                                  const unsigned short* __restrict__ csr,
                                                  const float* __restrict__ dinv,
                                                  const float* __restrict__ bias,
                                                  unsigned int* __restrict__ outc) {
    const int chunk = blockIdx.x / AGG_CH;
    const int nb = blockIdx.x % AGG_CH;
    const int wave = threadIdx.x >> 6, lane = threadIdx.x & 63;
    const int g = lane >> 4, u = lane & 15;
    const int n = nb * 16 + wave * 4 + g;
    const unsigned int* __restrict__ slice = hwc + (size_t)chunk * (NPAD * CHUNK_U);

    unsigned int sv = slice[n * CHUNK_U + u];  // self-loop term
    float ax = bf_lo(sv), ay = bf_hi(sv);

    const int2 se = rowse[n];  // start/end, both multiples of 8
    for (int i = se.x; i < se.y; i += 8) {
        uint4 c = *(const uint4*)&csr[i];  // 8 ushort srcs
        int s0 = c.x & 0xFFFF, s1 = c.x >> 16;
        int s2 = c.y & 0xFFFF, s3 = c.y >> 16;
        int s4 = c.z & 0xFFFF, s5 = c.z >> 16;
        int s6 = c.w & 0xFFFF, s7 = c.w >> 16;
        unsigned int v0 = slice[s0 * CHUNK_U + u], v1 = slice[s1 * CHUNK_U + u];
        unsigned int v2 = slice[s2 * CHUNK_U + u], v3 = slice[s3 * CHUNK_U + u];
        unsigned int v4 = slice[s4 * CHUNK_U + u], v5 = slice[s5 * CHUNK_U + u];
        unsigned int v6 = slice[s6 * CHUNK_U + u], v7 = slice[s7 * CHUNK_U + u];
        ax += bf_lo(v0) + bf_lo(v1) + bf_lo(v2) + bf_lo(v3) +
              bf_lo(v4) + bf_lo(v5) + bf_lo(v6) + bf_lo(v7);
        ay += bf_hi(v0) + bf_hi(v1) + bf_hi(v2) + bf_hi(v3) +
              bf_hi(v4) + bf_hi(v5) + bf_hi(v6) + bf_hi(v7);
    }

    float d = dinv[n];
    ax *= d;
    ay *= d;
    if (RELU_BIAS) {
        float2 bv = ((const float2*)bias)[chunk * CHUNK_U + u];
        ax = fmaxf(ax + bv.x, 0.f);
        ay = fmaxf(ay + bv.y, 0.f);
    }
    outc[(size_t)chunk * (NPAD * CHUNK_U) + n * CHUNK_U + u] = pack_bf16x2(ax, ay);
}

// ======== pooling: 1000 blocks x 50 nodes (5x TLP vs 200x250) ========
__global__ __launch_bounds__(256) void pool_kernel(const unsigned int* __restrict__ hbu,
                                                   const float* __restrict__ b4,
                                                   const int* __restrict__ batch,
                                                   float* __restrict__ pooled,
                                                   float* __restrict__ cnt) {
    __shared__ int bs[POOL_NODES];
    const int tid = threadIdx.x;
    const int n0 = blockIdx.x * POOL_NODES;
    if (tid < POOL_NODES) bs[tid] = batch[n0 + tid];
    __syncthreads();
    const int c2 = tid & 63;                 // feature-uint index 0..63
    const int chunk = c2 >> 4, u = c2 & 15;
    const int rsub = tid >> 6;  // 0..3
    float2 bb = ((const float2*)b4)[c2];
    float2 acc = {0.f, 0.f};
    float cacc = 0.f;
    int curg = bs[rsub];
    const size_t coff = (size_t)chunk * (NPAD * CHUNK_U) + u;
    for (int r = rsub; r < POOL_NODES; r += 4) {
        int g = bs[r];
        if (g != curg) {
            atomicAdd(&pooled[curg * H + c2 * 2], acc.x);
            atomicAdd(&pooled[curg * H + c2 * 2 + 1], acc.y);
            if (c2 == 0) atomicAdd(&cnt[curg], cacc);
            acc.x = acc.y = 0.f;
            cacc = 0.f;
            curg = g;
        }
        unsigned int v = hbu[coff + (size_t)(n0 + r) * CHUNK_U];
        acc.x += bf_lo(v) + bb.x;
        acc.y += bf_hi(v) + bb.y;
        cacc += 1.f;
    }
    atomicAdd(&pooled[curg * H + c2 * 2], acc.x);
    atomicAdd(&pooled[curg * H + c2 * 2 + 1], acc.y);
    if (c2 == 0) atomicAdd(&cnt[curg], cacc);
}

// ================= final MLP (single block) =================
__global__ __launch_bounds__(1024) void mlp_kernel(const float* __restrict__ pooled,
                                                   const float* __restrict__ cnt,
                                                   const float* __restrict__ lw1,
                                                   const float* __restrict__ lb1,
                                                   const float* __restrict__ lw2,
                                                   const float* __restrict__ lb2,
                                                   float* __restrict__ out) {
    __shared__ float mean_s[NG * H];
    __shared__ float hid_s[NG * 64];
    int tid = threadIdx.x;
    for (int i = tid; i < NG * H; i += 1024) {
        int g = i >> 7;
        mean_s[i] = pooled[i] / fmaxf(cnt[g], 1.0f);
    }
    __syncthreads();
    {
        int g = tid >> 6, j = tid & 63;
        float acc = lb1[j];
        for (int f = 0; f < H; f++) acc += mean_s[g * H + f] * lw1[f * 64 + j];
        hid_s[g * 64 + j] = fmaxf(acc, 0.f);
    }
    __syncthreads();
    if (tid < 32) {
        int g = tid >> 1, c = tid & 1;
        float acc = lb2[c];
        for (int j = 0; j < 64; j++) acc += hid_s[g * 64 + j] * lw2[j * 2 + c];
        out[g * 2 + c] = acc;
    }
}

extern "C" void kernel_launch(void* const* d_in, const int* in_sizes, int n_in,
                              void* d_out, int out_size, void* d_ws, size_t ws_size,
                              hipStream_t stream) {
    const float* x = (const float*)d_in[0];
    const int* ei = (const int*)d_in[1];
    const int* batch = (const int*)d_in[2];
    const float* W1 = (const float*)d_in[3];
    const float* b1 = (const float*)d_in[4];
    const float* W2 = (const float*)d_in[5];
    const float* b2 = (const float*)d_in[6];
    const float* W3 = (const float*)d_in[7];
    const float* b3 = (const float*)d_in[8];
    const float* W4 = (const float*)d_in[9];
    const float* b4 = (const float*)d_in[10];
    const float* lw1 = (const float*)d_in[11];
    const float* lb1 = (const float*)d_in[12];
    const float* lw2 = (const float*)d_in[13];
    const float* lb2 = (const float*)d_in[14];
    float* out = (float*)d_out;

    // workspace layout (4-byte units; sizes annotated in ints); ~39 MB
    int* wsi = (int*)d_ws;
    int* gcount = wsi;                                      // @0        128
    int* galloc = wsi + 128;                                // @128      1 (memset covers [0,256))
    int2* rowse = (int2*)(wsi + 512);                       // @512      100096 (NPAD int2)
    unsigned short* csr = (unsigned short*)(wsi + 100608);  // @100608   600000 (1.2M ushorts)
    float* dinv = (float*)(wsi + 700608);                   // @700608   50048
    unsigned short* Wt1 = (unsigned short*)(wsi + 750656);  // @750656   4096 (8192 shorts)
    unsigned short* Wt2 = (unsigned short*)(wsi + 754752);  // @754752   8192 (16384 shorts)
    unsigned short* Wt3 = (unsigned short*)(wsi + 762944);  // @762944   8192
    unsigned short* Wt4 = (unsigned short*)(wsi + 771136);  // @771136   8192
    unsigned short* xb = (unsigned short*)(wsi + 779328);   // @779328   1601536 (NPAD*64 shorts)
    unsigned int* hb = (unsigned int*)(wsi + 2380864);      // @2380864  3203072 (NPAD*64 uints)
    unsigned int* hwb = (unsigned int*)(wsi + 5583936);     // @5583936  3203072
    float* pooled = (float*)(wsi + 8787008);                // @8787008  2064 (NG*H+NG)
    float* pcnt = pooled + NG * H;
    unsigned int* ebuf = (unsigned int*)(wsi + 8789072);    // @8789072  980000 -> ends 9769072

    const int gemmBlocks = NPAD / 64;          // 782
    const int aggBlocks = 4 * AGG_CH;          // 12500, chunk-major

    // ---- CSR build + input/weight converts ----
    hipMemsetAsync(gcount, 0, 256 * sizeof(int), stream);  // gcount + galloc
    fillA_prep_kernel<<<FILLA_BLOCKS + PREP_BLOCKS, 256, 0, stream>>>(
        ei, gcount, ebuf, pooled, x, W1, W2, W3, W4, xb, Wt1, Wt2, Wt3, Wt4);
    fillB_kernel<<<NBUCK, 256, 0, stream>>>(ebuf, gcount, galloc, rowse, dinv, csr);

    // ---- layer 1 ----
    gemm_mfma_kernel<FIN><<<gemmBlocks, 256, 0, stream>>>(xb, Wt1, dinv, hwb);
    agg_kernel<true><<<aggBlocks, 256, 0, stream>>>(hwb, rowse, csr, dinv, b1, hb);
    // ---- layer 2 ----
    gemm_mfma_kernel<H><<<gemmBlocks, 256, 0, stream>>>((unsigned short*)hb, Wt2, dinv, hwb);
    agg_kernel<true><<<aggBlocks, 256, 0, stream>>>(hwb, rowse, csr, dinv, b2, hb);
    // ---- layer 3 ----
    gemm_mfma_kernel<H><<<gemmBlocks, 256, 0, stream>>>((unsigned short*)hb, Wt3, dinv, hwb);
    agg_kernel<true><<<aggBlocks, 256, 0, stream>>>(hwb, rowse, csr, dinv, b3, hb);
    // ---- layer 4 (no relu/bias; b4 fused in pool) ----
    gemm_mfma_kernel<H><<<gemmBlocks, 256, 0, stream>>>((unsigned short*)hb, Wt4, dinv, hwb);
    agg_kernel<false><<<aggBlocks, 256, 0, stream>>>(hwb, rowse, csr, dinv, nullptr, hb);

    // ---- pooling (fused +b4, pooled zeroed in fillA) + MLP ----
    pool_kernel<<<POOL_BLOCKS, 256, 0, stream>>>(hb, b4, batch, pooled, pcnt);
    mlp_kernel<<<1, 1024, 0, stream>>>(pooled, pcnt, lw1, lb1, lw2, lb2, out);
}

// Round 19
// 343.240 us; speedup vs baseline: 1.1736x; 1.1189x over previous
//
#include <hip/hip_runtime.h>

#define NN 50000
#define NPAD 50048   // rows padded to multiple of 64 for MFMA tiles
#define NE 800000
#define FIN 64
#define H 128
#define NG 16
#define POOL_BLOCKS 1000
#define POOL_NODES 50
#define NPART 64         // private pooled-accumulator copies (atomic spreading)
#define NBUCK 98         // buckets of 512 dst nodes
#define BUCK_CAP 10000   // edges per bucket capacity (expected 8163 +- 90)
#define FILLA_BLOCKS 512
#define FILLA_CHUNK 1563  // ceil(NE / FILLA_BLOCKS)
#define CHUNK_U 16       // uints per node per feature-chunk (32 feats)
#define DUMMY NN         // zero pad row used for CSR padding
#define AGG_CH (NN / 16) // 3125 blocks per chunk
#define PREP_ITEMS (NPAD * FIN + H * FIN + 3 * H * H)
#define PREP_BLOCKS ((PREP_ITEMS + 255) / 256)

typedef __bf16 bf16x8 __attribute__((ext_vector_type(8)));
typedef float f32x4 __attribute__((ext_vector_type(4)));

// ---- helpers ----
__device__ inline unsigned short bf16r(float x) {
    unsigned int u = __float_as_uint(x);
    return (unsigned short)((u + 0x7fffu + ((u >> 16) & 1u)) >> 16);
}
__device__ inline unsigned int pack_bf16x2(float a, float b) {
    return (unsigned int)bf16r(a) | ((unsigned int)bf16r(b) << 16);
}
__device__ inline float bf_lo(unsigned int u) { return __uint_as_float(u << 16); }
__device__ inline float bf_hi(unsigned int u) { return __uint_as_float(u & 0xffff0000u); }

// ====== fillA + prep merged: blocks [0,512) bucket edges; rest convert x/W ======
__global__ __launch_bounds__(256) void fillA_prep_kernel(const int* __restrict__ ei,
                                                         int* __restrict__ gcount,
                                                         unsigned int* __restrict__ ebuf,
                                                         const float* __restrict__ x,
                                                         const float* __restrict__ W1,
                                                         const float* __restrict__ W2,
                                                         const float* __restrict__ W3,
                                                         const float* __restrict__ W4,
                                                         unsigned short* __restrict__ xb,
                                                         unsigned short* __restrict__ Wt1,
                                                         unsigned short* __restrict__ Wt2,
                                                         unsigned short* __restrict__ Wt3,
                                                         unsigned short* __restrict__ Wt4) {
    const int t = threadIdx.x;
    if (blockIdx.x >= FILLA_BLOCKS) {
        // ---- prep part ----
        int e = (blockIdx.x - FILLA_BLOCKS) * 256 + t;
        if (e < NPAD * FIN) {
            int n = e >> 6, k = e & 63;
            unsigned short v = (n < NN) ? bf16r(x[n * FIN + k]) : (unsigned short)0;
            xb[(size_t)(k >> 5) * (NPAD * 32) + n * 32 + (k & 31)] = v;
            return;
        }
        int tt = e - NPAD * FIN;
        if (tt < H * FIN) {
            int n = tt / FIN, k = tt % FIN;
            Wt1[tt] = bf16r(W1[k * H + n]);
            return;
        }
        int u = tt - H * FIN;
        const float* W = W2;
        unsigned short* Wt = Wt2;
        if (u >= 2 * H * H) { W = W4; Wt = Wt4; u -= 2 * H * H; }
        else if (u >= H * H) { W = W3; Wt = Wt3; u -= H * H; }
        if (u < H * H) {
            int n = u / H, k = u % H;
            Wt[u] = bf16r(W[k * H + n]);
        }
        return;
    }
    // ---- fillA part ----
    __shared__ int hist[128];
    __shared__ int base[128];
    if (t < 128) hist[t] = 0;
    __syncthreads();
    const int e0 = blockIdx.x * FILLA_CHUNK;
    const int e1 = min(e0 + FILLA_CHUNK, NE);
    for (int e = e0 + t; e < e1; e += 256)
        atomicAdd(&hist[ei[NE + e] >> 9], 1);
    __syncthreads();
    if (t < 128) {
        int h = (t < NBUCK) ? hist[t] : 0;
        base[t] = h ? atomicAdd(&gcount[t], h) : 0;
    }
    __syncthreads();
    for (int e = e0 + t; e < e1; e += 256) {
        int d = ei[NE + e];
        int s = ei[e];
        int b = d >> 9;
        int pos = atomicAdd(&base[b], 1);
        ebuf[b * BUCK_CAP + pos] = (unsigned int)s | ((unsigned int)d << 16);
    }
}

// fillB (fused hist+scan+scatter): per bucket: LDS hist -> padded counts ->
// local scan -> one global atomicAdd reserves the bucket's csr window ->
// rowse (start,end) + dinv + LDS-cursor scatter + DUMMY pads.
__global__ __launch_bounds__(256) void fillB_kernel(const unsigned int* __restrict__ ebuf,
                                                    const int* __restrict__ gcount,
                                                    int* __restrict__ galloc,
                                                    int2* __restrict__ rowse,
                                                    float* __restrict__ dinv,
                                                    unsigned short* __restrict__ csr) {
    __shared__ int lh[512];
    __shared__ int lsum[256];
    __shared__ int loff[512];
    __shared__ int lcur[512];
    __shared__ int base_s;
    const int b = blockIdx.x, t = threadIdx.x;
    const int n0 = b * 512;
    lh[t] = 0;
    lh[t + 256] = 0;
    __syncthreads();
    const int ne = gcount[b];
    const unsigned int* __restrict__ eb = ebuf + b * BUCK_CAP;
    for (int i = t; i < ne; i += 256)
        atomicAdd(&lh[(int)(eb[i] >> 16) - n0], 1);
    __syncthreads();
    const int c0 = lh[2 * t], c1 = lh[2 * t + 1];
    const int p0 = (c0 + 7) & ~7, p1 = (c1 + 7) & ~7;
    lsum[t] = p0 + p1;
    __syncthreads();
    for (int off = 1; off < 256; off <<= 1) {
        int u = (t >= off) ? lsum[t - off] : 0;
        __syncthreads();
        lsum[t] += u;
        __syncthreads();
    }
    if (t == 255) base_s = atomicAdd(galloc, lsum[255]);
    int excl = (t == 0) ? 0 : lsum[t - 1];
    __syncthreads();
    const int base = base_s;
    loff[2 * t] = excl;
    loff[2 * t + 1] = excl + p0;
    {
        int j = 2 * t, n = n0 + j;
        int st = base + excl;
        if (n < NN) {
            rowse[n] = make_int2(st, st + p0);
            dinv[n] = rsqrtf((float)c0 + 1.0f);  // +1 self-loop
        } else if (n < NPAD) {
            rowse[n] = make_int2(0, 0);
            dinv[n] = 0.0f;
        }
        lcur[j] = st;
        int st1 = st + p0, n1 = n + 1;
        if (n1 < NN) {
            rowse[n1] = make_int2(st1, st1 + p1);
            dinv[n1] = rsqrtf((float)c1 + 1.0f);
        } else if (n1 < NPAD) {
            rowse[n1] = make_int2(0, 0);
            dinv[n1] = 0.0f;
        }
        lcur[j + 1] = st1;
    }
    __syncthreads();
    for (int i = t; i < ne; i += 256) {
        unsigned int u = eb[i];
        int s = (int)(u & 0xFFFFu);
        int j = (int)(u >> 16) - n0;
        int pos = atomicAdd(&lcur[j], 1);
        csr[pos] = (unsigned short)s;
    }
    __syncthreads();
    {
        int j = 2 * t;
        int st = base + loff[j] + c0, en = base + loff[j] + p0;
        for (int k = st; k < en; k++) csr[k] = (unsigned short)DUMMY;
        int st1 = base + loff[j + 1] + c1, en1 = base + loff[j + 1] + p1;
        for (int k = st1; k < en1; k++) csr[k] = (unsigned short)DUMMY;
    }
}

// ===== MFMA GEMM (chunked in/out): hw' = (h @ W) * dinv[row], bf16 out =====
#define LSTRIDE 130
template <int K>
__global__ __launch_bounds__(256) void gemm_mfma_kernel(const unsigned short* __restrict__ hb,
                                                        const unsigned short* __restrict__ Wt,
                                                        const float* __restrict__ dinv,
                                                        unsigned int* __restrict__ outu) {
    __shared__ float ls[64 * LSTRIDE];  // ~33 KB
    const int wave = threadIdx.x >> 6, lane = threadIdx.x & 63;
    const int m15 = lane & 15, quad = lane >> 4;
    const int row0 = blockIdx.x * 64;
    const int arow = row0 + wave * 16 + m15;

    bf16x8 a[K / 32];
#pragma unroll
    for (int ks = 0; ks < K / 32; ks++)
        a[ks] = *(const bf16x8*)&hb[(size_t)ks * (NPAD * 32) + arow * 32 + quad * 8];

    const int lrow = wave * 16 + quad * 4;
    float dv[4];
#pragma unroll
    for (int r = 0; r < 4; r++) dv[r] = dinv[row0 + lrow + r];

#pragma unroll
    for (int ct = 0; ct < 8; ct++) {
        f32x4 acc = {0.f, 0.f, 0.f, 0.f};
#pragma unroll
        for (int ks = 0; ks < K / 32; ks++) {
            bf16x8 b = *(const bf16x8*)&Wt[(ct * 16 + m15) * K + ks * 32 + quad * 8];
            acc = __builtin_amdgcn_mfma_f32_16x16x32_bf16(a[ks], b, acc, 0, 0, 0);
        }
#pragma unroll
        for (int r = 0; r < 4; r++)
            ls[(lrow + r) * LSTRIDE + ct * 16 + m15] = acc[r] * dv[r];
    }
    __syncthreads();

#pragma unroll
    for (int k = 0; k < 4; k++) {
        int idx = threadIdx.x + 256 * k;
        int c = idx >> 8, row = (idx >> 2) & 63, q = idx & 3;
        const float* p = &ls[row * LSTRIDE + c * 32 + q * 8];
        uint4 o;
        o.x = pack_bf16x2(p[0], p[1]);
        o.y = pack_bf16x2(p[2], p[3]);
        o.z = pack_bf16x2(p[4], p[5]);
        o.w = pack_bf16x2(p[6], p[7]);
        *(uint4*)&outu[(size_t)c * (NPAD * CHUNK_U) + (size_t)(row0 + row) * CHUNK_U + q * 4] = o;
    }
}

// ====== feature-chunked gather aggregation, one node per 16-lane group ======
template <bool RELU_BIAS>
__global__ __launch_bounds__(256) void agg_kernel(const unsigned int* __restrict__ hwc,
                                                  const int2* __restrict__ rowse,
                                                  const unsigned short* __restrict__ csr,
                                                  const float* __restrict__ dinv,
                                                  const float* __restrict__ bias,
                                                  unsigned int* __restrict__ outc) {
    const int chunk = blockIdx.x / AGG_CH;
    const int nb = blockIdx.x % AGG_CH;
    const int wave = threadIdx.x >> 6, lane = threadIdx.x & 63;
    const int g = lane >> 4, u = lane & 15;
    const int n = nb * 16 + wave * 4 + g;
    const unsigned int* __restrict__ slice = hwc + (size_t)chunk * (NPAD * CHUNK_U);

    unsigned int sv = slice[n * CHUNK_U + u];  // self-loop term
    float ax = bf_lo(sv), ay = bf_hi(sv);

    const int2 se = rowse[n];  // start/end, both multiples of 8
    for (int i = se.x; i < se.y; i += 8) {
        uint4 c = *(const uint4*)&csr[i];  // 8 ushort srcs
        int s0 = c.x & 0xFFFF, s1 = c.x >> 16;
        int s2 = c.y & 0xFFFF, s3 = c.y >> 16;
        int s4 = c.z & 0xFFFF, s5 = c.z >> 16;
        int s6 = c.w & 0xFFFF, s7 = c.w >> 16;
        unsigned int v0 = slice[s0 * CHUNK_U + u], v1 = slice[s1 * CHUNK_U + u];
        unsigned int v2 = slice[s2 * CHUNK_U + u], v3 = slice[s3 * CHUNK_U + u];
        unsigned int v4 = slice[s4 * CHUNK_U + u], v5 = slice[s5 * CHUNK_U + u];
        unsigned int v6 = slice[s6 * CHUNK_U + u], v7 = slice[s7 * CHUNK_U + u];
        ax += bf_lo(v0) + bf_lo(v1) + bf_lo(v2) + bf_lo(v3) +
              bf_lo(v4) + bf_lo(v5) + bf_lo(v6) + bf_lo(v7);
        ay += bf_hi(v0) + bf_hi(v1) + bf_hi(v2) + bf_hi(v3) +
              bf_hi(v4) + bf_hi(v5) + bf_hi(v6) + bf_hi(v7);
    }

    float d = dinv[n];
    ax *= d;
    ay *= d;
    if (RELU_BIAS) {
        float2 bv = ((const float2*)bias)[chunk * CHUNK_U + u];
        ax = fmaxf(ax + bv.x, 0.f);
        ay = fmaxf(ay + bv.y, 0.f);
    }
    outc[(size_t)chunk * (NPAD * CHUNK_U) + n * CHUNK_U + u] = pack_bf16x2(ax, ay);
}

// ======== pooling: 1000 blocks x 50 nodes; atomics spread over NPART copies ========
__global__ __launch_bounds__(256) void pool_kernel(const unsigned int* __restrict__ hbu,
                                                   const float* __restrict__ b4,
                                                   const int* __restrict__ batch,
                                                   float* __restrict__ poolpart,
                                                   float* __restrict__ pcntpart) {
    __shared__ int bs[POOL_NODES];
    const int tid = threadIdx.x;
    const int n0 = blockIdx.x * POOL_NODES;
    if (tid < POOL_NODES) bs[tid] = batch[n0 + tid];
    __syncthreads();
    float* __restrict__ pooled = poolpart + (blockIdx.x & (NPART - 1)) * (NG * H);
    float* __restrict__ cnt = pcntpart + (blockIdx.x & (NPART - 1)) * NG;
    const int c2 = tid & 63;                 // feature-uint index 0..63
    const int chunk = c2 >> 4, u = c2 & 15;
    const int rsub = tid >> 6;  // 0..3
    float2 bb = ((const float2*)b4)[c2];
    float2 acc = {0.f, 0.f};
    float cacc = 0.f;
    int curg = bs[rsub];
    const size_t coff = (size_t)chunk * (NPAD * CHUNK_U) + u;
    for (int r = rsub; r < POOL_NODES; r += 4) {
        int g = bs[r];
        if (g != curg) {
            atomicAdd(&pooled[curg * H + c2 * 2], acc.x);
            atomicAdd(&pooled[curg * H + c2 * 2 + 1], acc.y);
            if (c2 == 0) atomicAdd(&cnt[curg], cacc);
            acc.x = acc.y = 0.f;
            cacc = 0.f;
            curg = g;
        }
        unsigned int v = hbu[coff + (size_t)(n0 + r) * CHUNK_U];
        acc.x += bf_lo(v) + bb.x;
        acc.y += bf_hi(v) + bb.y;
        cacc += 1.f;
    }
    atomicAdd(&pooled[curg * H + c2 * 2], acc.x);
    atomicAdd(&pooled[curg * H + c2 * 2 + 1], acc.y);
    if (c2 == 0) atomicAdd(&cnt[curg], cacc);
}

// ============ final MLP (single block): reduce NPART copies, then GEMMs ============
__global__ __launch_bounds__(1024) void mlp_kernel(const float* __restrict__ poolpart,
                                                   const float* __restrict__ pcntpart,
                                                   const float* __restrict__ lw1,
                                                   const float* __restrict__ lb1,
                                                   const float* __restrict__ lw2,
                                                   const float* __restrict__ lb2,
                                                   float* __restrict__ out) {
    __shared__ float mean_s[NG * H];
    __shared__ float cnt_s[NG];
    __shared__ float hid_s[NG * 64];
    int tid = threadIdx.x;
    if (tid < NG) {
        float c = 0.f;
        for (int p = 0; p < NPART; p++) c += pcntpart[p * NG + tid];
        cnt_s[tid] = fmaxf(c, 1.0f);
    }
    __syncthreads();
    for (int i = tid; i < NG * H; i += 1024) {
        float s = 0.f;
        for (int p = 0; p < NPART; p++) s += poolpart[p * (NG * H) + i];
        mean_s[i] = s / cnt_s[i >> 7];
    }
    __syncthreads();
    {
        int g = tid >> 6, j = tid & 63;
        float acc = lb1[j];
        for (int f = 0; f < H; f++) acc += mean_s[g * H + f] * lw1[f * 64 + j];
        hid_s[g * 64 + j] = fmaxf(acc, 0.f);
    }
    __syncthreads();
    if (tid < 32) {
        int g = tid >> 1, c = tid & 1;
        float acc = lb2[c];
        for (int j = 0; j < 64; j++) acc += hid_s[g * 64 + j] * lw2[j * 2 + c];
        out[g * 2 + c] = acc;
    }
}

extern "C" void kernel_launch(void* const* d_in, const int* in_sizes, int n_in,
                              void* d_out, int out_size, void* d_ws, size_t ws_size,
                              hipStream_t stream) {
    const float* x = (const float*)d_in[0];
    const int* ei = (const int*)d_in[1];
    const int* batch = (const int*)d_in[2];
    const float* W1 = (const float*)d_in[3];
    const float* b1 = (const float*)d_in[4];
    const float* W2 = (const float*)d_in[5];
    const float* b2 = (const float*)d_in[6];
    const float* W3 = (const float*)d_in[7];
    const float* b3 = (const float*)d_in[8];
    const float* W4 = (const float*)d_in[9];
    const float* b4 = (const float*)d_in[10];
    const float* lw1 = (const float*)d_in[11];
    const float* lb1 = (const float*)d_in[12];
    const float* lw2 = (const float*)d_in[13];
    const float* lb2 = (const float*)d_in[14];
    float* out = (float*)d_out;

    // workspace layout (4-byte units; sizes annotated in ints); ~40 MB
    int* wsi = (int*)d_ws;
    int* gcount = wsi;                                      // @0        128
    int* galloc = wsi + 128;                                // @128      1 (pad to 256)
    float* poolpart = (float*)(wsi + 256);                  // @256      131072 (NPART*NG*H)
    float* pcntpart = (float*)(wsi + 131328);               // @131328   1024 (NPART*NG)
    int2* rowse = (int2*)(wsi + 132352);                    // @132352   100096 (NPAD int2)
    unsigned short* csr = (unsigned short*)(wsi + 232448);  // @232448   600000 (1.2M ushorts)
    float* dinv = (float*)(wsi + 832448);                   // @832448   50048
    unsigned short* Wt1 = (unsigned short*)(wsi + 882496);  // @882496   4096 (8192 shorts)
    unsigned short* Wt2 = (unsigned short*)(wsi + 886592);  // @886592   8192 (16384 shorts)
    unsigned short* Wt3 = (unsigned short*)(wsi + 894784);  // @894784   8192
    unsigned short* Wt4 = (unsigned short*)(wsi + 902976);  // @902976   8192
    unsigned short* xb = (unsigned short*)(wsi + 911168);   // @911168   1601536 (NPAD*64 shorts)
    unsigned int* hb = (unsigned int*)(wsi + 2512704);      // @2512704  3203072 (NPAD*64 uints)
    unsigned int* hwb = (unsigned int*)(wsi + 5715776);     // @5715776  3203072
    unsigned int* ebuf = (unsigned int*)(wsi + 8918848);    // @8918848  980000 -> ends 9898848

    const int gemmBlocks = NPAD / 64;          // 782
    const int aggBlocks = 4 * AGG_CH;          // 12500, chunk-major

    // ---- zero control vars + pool partials (one memset), CSR build + converts ----
    hipMemsetAsync(wsi, 0, 132352 * sizeof(int), stream);
    fillA_prep_kernel<<<FILLA_BLOCKS + PREP_BLOCKS, 256, 0, stream>>>(
        ei, gcount, ebuf, x, W1, W2, W3, W4, xb, Wt1, Wt2, Wt3, Wt4);
    fillB_kernel<<<NBUCK, 256, 0, stream>>>(ebuf, gcount, galloc, rowse, dinv, csr);

    // ---- layer 1 ----
    gemm_mfma_kernel<FIN><<<gemmBlocks, 256, 0, stream>>>(xb, Wt1, dinv, hwb);
    agg_kernel<true><<<aggBlocks, 256, 0, stream>>>(hwb, rowse, csr, dinv, b1, hb);
    // ---- layer 2 ----
    gemm_mfma_kernel<H><<<gemmBlocks, 256, 0, stream>>>((unsigned short*)hb, Wt2, dinv, hwb);
    agg_kernel<true><<<aggBlocks, 256, 0, stream>>>(hwb, rowse, csr, dinv, b2, hb);
    // ---- layer 3 ----
    gemm_mfma_kernel<H><<<gemmBlocks, 256, 0, stream>>>((unsigned short*)hb, Wt3, dinv, hwb);
    agg_kernel<true><<<aggBlocks, 256, 0, stream>>>(hwb, rowse, csr, dinv, b3, hb);
    // ---- layer 4 (no relu/bias; b4 fused in pool) ----
    gemm_mfma_kernel<H><<<gemmBlocks, 256, 0, stream>>>((unsigned short*)hb, Wt4, dinv, hwb);
    agg_kernel<false><<<aggBlocks, 256, 0, stream>>>(hwb, rowse, csr, dinv, nullptr, hb);

    // ---- pooling (fused +b4, partials zeroed in memset) + MLP ----
    pool_kernel<<<POOL_BLOCKS, 256, 0, stream>>>(hb, b4, batch, poolpart, pcntpart);
    mlp_kernel<<<1, 1024, 0, stream>>>(poolpart, pcntpart, lw1, lb1, lw2, lb2, out);
}